// Round 1
// baseline (363.644 us; speedup 1.0000x reference)
//
#include <hip/hip_runtime.h>
#include <math.h>

#define V_   6890
#define FC_  13776
#define N_   2
#define H_   336
#define W_   336
#define K_   28
#define NPIX (N_*H_*W_)

// constants from the reference
#define SIGMA_INV 1.0e4f    // 1/SIGMA
#define GAMMA_INV 1.0e4f    // 1/GAMMA
#define EPS_      1e-10f
#define ZFAR_     100.0f
#define ZNEAR_    1.0f
#define ZSCALE    (1.0f/(ZFAR_-ZNEAR_))   // 1/99

// ws layout: [0, 3*V floats) vertex-normal accumulator; then face table
#define FD_OFFSET 82944   // align_up(3*6890*4, 256); 16B aligned
// face table: 28 floats per face:
//  [0..2] p0 [3..5] p1 [6..8] p2 [9..11] n0 [12..14] n1 [15..17] n2
//  [18..20] c0 [21..23] c1 [24..26] c2 [27] pad

__global__ __launch_bounds__(256)
void face_pass1(const float* __restrict__ verts,
                const float* __restrict__ vcol,
                const int*   __restrict__ faces,
                float* __restrict__ vnAcc,
                float* __restrict__ fd) {
    int i = blockIdx.x * blockDim.x + threadIdx.x;
    if (i >= FC_) return;
    int f0 = faces[i*3+0], f1 = faces[i*3+1], f2 = faces[i*3+2];
    float p0x = verts[f0*3+0], p0y = verts[f0*3+1], p0z = verts[f0*3+2];
    float p1x = verts[f1*3+0], p1y = verts[f1*3+1], p1z = verts[f1*3+2];
    float p2x = verts[f2*3+0], p2y = verts[f2*3+1], p2z = verts[f2*3+2];
    float e1x = p1x - p0x, e1y = p1y - p0y, e1z = p1z - p0z;
    float e2x = p2x - p0x, e2y = p2y - p0y, e2z = p2z - p0z;
    float fnx = e1y*e2z - e1z*e2y;
    float fny = e1z*e2x - e1x*e2z;
    float fnz = e1x*e2y - e1y*e2x;
    atomicAdd(&vnAcc[f0*3+0], fnx); atomicAdd(&vnAcc[f0*3+1], fny); atomicAdd(&vnAcc[f0*3+2], fnz);
    atomicAdd(&vnAcc[f1*3+0], fnx); atomicAdd(&vnAcc[f1*3+1], fny); atomicAdd(&vnAcc[f1*3+2], fnz);
    atomicAdd(&vnAcc[f2*3+0], fnx); atomicAdd(&vnAcc[f2*3+1], fny); atomicAdd(&vnAcc[f2*3+2], fnz);
    float* o = fd + (size_t)i * 28;
    o[0] = p0x; o[1] = p0y; o[2] = p0z;
    o[3] = p1x; o[4] = p1y; o[5] = p1z;
    o[6] = p2x; o[7] = p2y; o[8] = p2z;
    o[18] = vcol[f0*3+0]; o[19] = vcol[f0*3+1]; o[20] = vcol[f0*3+2];
    o[21] = vcol[f1*3+0]; o[22] = vcol[f1*3+1]; o[23] = vcol[f1*3+2];
    o[24] = vcol[f2*3+0]; o[25] = vcol[f2*3+1]; o[26] = vcol[f2*3+2];
    o[27] = 0.0f;
}

__global__ __launch_bounds__(256)
void vn_normalize(float* __restrict__ vn) {
    int i = blockIdx.x * blockDim.x + threadIdx.x;
    if (i >= V_) return;
    float x = vn[i*3+0], y = vn[i*3+1], z = vn[i*3+2];
    float n = sqrtf(x*x + y*y + z*z);
    float inv = 1.0f / fmaxf(n, 1e-6f);
    vn[i*3+0] = x*inv; vn[i*3+1] = y*inv; vn[i*3+2] = z*inv;
}

__global__ __launch_bounds__(256)
void face_pass2(const int* __restrict__ faces,
                const float* __restrict__ vn,
                float* __restrict__ fd) {
    int i = blockIdx.x * blockDim.x + threadIdx.x;
    if (i >= FC_) return;
    int f0 = faces[i*3+0], f1 = faces[i*3+1], f2 = faces[i*3+2];
    float* o = fd + (size_t)i * 28;
    o[9]  = vn[f0*3+0]; o[10] = vn[f0*3+1]; o[11] = vn[f0*3+2];
    o[12] = vn[f1*3+0]; o[13] = vn[f1*3+1]; o[14] = vn[f1*3+2];
    o[15] = vn[f2*3+0]; o[16] = vn[f2*3+1]; o[17] = vn[f2*3+2];
}

__global__ __launch_bounds__(256)
void pixel_kernel(const int*   __restrict__ ptf,
                  const float* __restrict__ bary,
                  const float* __restrict__ dists,
                  const float* __restrict__ zbuf,
                  const float4* __restrict__ fd,   // 7 float4 per face
                  const float* __restrict__ light,
                  const float* __restrict__ amb,
                  const float* __restrict__ dif,
                  const float* __restrict__ spec,
                  const float* __restrict__ cam,
                  float* __restrict__ out) {
    int pix = blockIdx.x * blockDim.x + threadIdx.x;
    if (pix >= NPIX) return;

    float lx = light[0], ly = light[1], lz = light[2];
    float ax = amb[0],   ay = amb[1],   az = amb[2];
    float dcx = dif[0],  dcy = dif[1],  dcz = dif[2];
    float scx = spec[0], scy = spec[1], scz = spec[2];
    float camx = cam[0], camy = cam[1], camz = cam[2];

    const float4* bp = (const float4*)(bary  + (size_t)pix * (K_*3));
    const int4*   pp = (const int4*)  (ptf   + (size_t)pix * K_);
    const float4* dp = (const float4*)(dists + (size_t)pix * K_);
    const float4* zp = (const float4*)(zbuf  + (size_t)pix * K_);
    float4* zout = (float4*)(out + (size_t)NPIX*4 + (size_t)pix * K_);

    float m = EPS_;          // running max of z_inv (ref clamps at EPS)
    float ssum = 0.0f;       // running sum of w_num (relative to m)
    float accr = 0.0f, accg = 0.0f, accb = 0.0f;
    float omp = 1.0f;        // prod(1 - prob)

    for (int kg = 0; kg < K_/4; ++kg) {
        float4 b0 = bp[kg*3+0], b1 = bp[kg*3+1], b2 = bp[kg*3+2];
        int4   pf4 = pp[kg];
        float4 d4  = dp[kg];
        float4 z4  = zp[kg];
        zout[kg] = z4;  // zbuf passthrough (second output)

        const float barr[12] = {b0.x,b0.y,b0.z,b0.w,b1.x,b1.y,b1.z,b1.w,b2.x,b2.y,b2.z,b2.w};
        const int   pfar[4]  = {pf4.x,pf4.y,pf4.z,pf4.w};
        const float darr[4]  = {d4.x,d4.y,d4.z,d4.w};
        const float zarr[4]  = {z4.x,z4.y,z4.z,z4.w};

        #pragma unroll
        for (int j = 0; j < 4; ++j) {
            int pf = pfar[j];
            if (pf < 0) continue;   // masked: prob=0, z_inv=0 -> no contribution at all

            float prob = 1.0f / (1.0f + expf(darr[j] * SIGMA_INV)); // sigmoid(-d/sigma)

            float w0 = barr[j*3+0], w1 = barr[j*3+1], w2 = barr[j*3+2];

            const float4* fq = fd + (size_t)pf * 7;
            float4 q0 = fq[0], q1 = fq[1], q2 = fq[2], q3 = fq[3];
            float4 q4 = fq[4], q5 = fq[5], q6 = fq[6];
            float p0x=q0.x,p0y=q0.y,p0z=q0.z;
            float p1x=q0.w,p1y=q1.x,p1z=q1.y;
            float p2x=q1.z,p2y=q1.w,p2z=q2.x;
            float n0x=q2.y,n0y=q2.z,n0z=q2.w;
            float n1x=q3.x,n1y=q3.y,n1z=q3.z;
            float n2x=q3.w,n2y=q4.x,n2z=q4.y;
            float c0x=q4.z,c0y=q4.w,c0z=q5.x;
            float c1x=q5.y,c1y=q5.z,c1z=q5.w;
            float c2x=q6.x,c2y=q6.y,c2z=q6.z;

            // interpolate position / normal / texel
            float px = w0*p0x + w1*p1x + w2*p2x;
            float py = w0*p0y + w1*p1y + w2*p2y;
            float pz = w0*p0z + w1*p1z + w2*p2z;
            float nux = w0*n0x + w1*n1x + w2*n2x;
            float nuy = w0*n0y + w1*n1y + w2*n2y;
            float nuz = w0*n0z + w1*n1z + w2*n2z;
            float ninv = 1.0f / fmaxf(sqrtf(nux*nux + nuy*nuy + nuz*nuz), 1e-6f);
            float nx = nux*ninv, ny = nuy*ninv, nz = nuz*ninv;
            float tr = w0*c0x + w1*c1x + w2*c2x;
            float tg = w0*c0y + w1*c1y + w2*c2y;
            float tb = w0*c0z + w1*c1z + w2*c2z;

            // light dir
            float lvx = lx - px, lvy = ly - py, lvz = lz - pz;
            float linv = 1.0f / fmaxf(sqrtf(lvx*lvx + lvy*lvy + lvz*lvz), 1e-6f);
            lvx *= linv; lvy *= linv; lvz *= linv;
            float ldn = lvx*nx + lvy*ny + lvz*nz;      // unclamped dot(l, n)
            float ndotl = fmaxf(ldn, 0.0f);

            // view dir
            float vvx = camx - px, vvy = camy - py, vvz = camz - pz;
            float vinv = 1.0f / fmaxf(sqrtf(vvx*vvx + vvy*vvy + vvz*vvz), 1e-6f);
            vvx *= vinv; vvy *= vinv; vvz *= vinv;

            // reflect = -l + 2*dot(l,n)*n
            float rx = 2.0f*ldn*nx - lvx;
            float ry = 2.0f*ldn*ny - lvy;
            float rz = 2.0f*ldn*nz - lvz;
            float ca = fmaxf(rx*vvx + ry*vvy + rz*vvz, 0.0f);
            float p64 = ca*ca;           // ^2
            p64 *= p64;                  // ^4
            p64 *= p64;                  // ^8
            p64 *= p64;                  // ^16
            p64 *= p64;                  // ^32
            p64 *= p64;                  // ^64

            float cr = (ax + dcx*ndotl)*tr + scx*p64;
            float cg = (ay + dcy*ndotl)*tg + scy*p64;
            float cb = (az + dcz*ndotl)*tb + scz*p64;

            // soft-z blend with online max rescale
            float zi = (ZFAR_ - zarr[j]) * ZSCALE;
            float w;
            if (zi > m) {
                float scale = expf((m - zi) * GAMMA_INV);
                ssum *= scale; accr *= scale; accg *= scale; accb *= scale;
                m = zi;
                w = prob;                          // exp(0) = 1
            } else {
                w = prob * expf((zi - m) * GAMMA_INV);
            }
            ssum += w;
            accr += w*cr; accg += w*cg; accb += w*cb;
            omp *= (1.0f - prob);
        }
    }

    float deltaw = expf((EPS_ - m) * GAMMA_INV);
    float inv = 1.0f / (ssum + deltaw);
    float4 img;
    img.x = (accr + deltaw) * inv;   // BG = 1
    img.y = (accg + deltaw) * inv;
    img.z = (accb + deltaw) * inv;
    img.w = 1.0f - omp;
    ((float4*)out)[pix] = img;
}

extern "C" void kernel_launch(void* const* d_in, const int* in_sizes, int n_in,
                              void* d_out, int out_size, void* d_ws, size_t ws_size,
                              hipStream_t stream) {
    const float* verts = (const float*)d_in[0];
    const float* vcol  = (const float*)d_in[1];
    const int*   faces = (const int*)d_in[2];
    const int*   ptf   = (const int*)d_in[3];
    const float* bary  = (const float*)d_in[4];
    const float* dists = (const float*)d_in[5];
    const float* zbuf  = (const float*)d_in[6];
    const float* light = (const float*)d_in[7];
    const float* amb   = (const float*)d_in[8];
    const float* dif   = (const float*)d_in[9];
    const float* spec  = (const float*)d_in[10];
    const float* cam   = (const float*)d_in[11];
    float* out = (float*)d_out;

    float* vnAcc = (float*)d_ws;
    float* fdat  = (float*)((char*)d_ws + FD_OFFSET);

    hipMemsetAsync(vnAcc, 0, (size_t)V_ * 3 * sizeof(float), stream);
    face_pass1<<<(FC_ + 255)/256, 256, 0, stream>>>(verts, vcol, faces, vnAcc, fdat);
    vn_normalize<<<(V_ + 255)/256, 256, 0, stream>>>(vnAcc);
    face_pass2<<<(FC_ + 255)/256, 256, 0, stream>>>(faces, vnAcc, fdat);
    pixel_kernel<<<(NPIX + 255)/256, 256, 0, stream>>>(
        ptf, bary, dists, zbuf, (const float4*)fdat,
        light, amb, dif, spec, cam, out);
}

// Round 2
// 261.397 us; speedup vs baseline: 1.3912x; 1.3912x over previous
//
#include <hip/hip_runtime.h>
#include <hip/hip_fp16.h>
#include <math.h>

#define V_   6890
#define FC_  13776
#define N_   2
#define H_   336
#define W_   336
#define K_   28
#define NPIX (N_*H_*W_)

#define SIGMA_INV 1.0e4f
#define GAMMA_INV 1.0e4f
#define EPS_      1e-10f
#define ZFAR_     100.0f
#define ZSCALE    (1.0f/99.0f)

// ws layout: [0, 3*V floats) vertex-normal accumulator (fp32, atomics);
// then fp16 face table, 32 halfs (64 B) per face:
//   halfs 0..8  : p0,p1,p2      (written by face_pass1)
//   halfs 9..17 : c0,c1,c2      (written by face_pass1)
//   halfs 18..26: n0,n1,n2      (written by face_pass2)
//   halfs 27..31: pad
#define FD_OFFSET 82944   // align_up(3*6890*4, 256)

__global__ __launch_bounds__(256)
void face_pass1(const float* __restrict__ verts,
                const float* __restrict__ vcol,
                const int*   __restrict__ faces,
                float* __restrict__ vnAcc,
                __half2* __restrict__ fd) {
    int i = blockIdx.x * blockDim.x + threadIdx.x;
    if (i >= FC_) return;
    int f0 = faces[i*3+0], f1 = faces[i*3+1], f2 = faces[i*3+2];
    float a[18];
    a[0] = verts[f0*3+0]; a[1] = verts[f0*3+1]; a[2] = verts[f0*3+2];
    a[3] = verts[f1*3+0]; a[4] = verts[f1*3+1]; a[5] = verts[f1*3+2];
    a[6] = verts[f2*3+0]; a[7] = verts[f2*3+1]; a[8] = verts[f2*3+2];
    float e1x = a[3]-a[0], e1y = a[4]-a[1], e1z = a[5]-a[2];
    float e2x = a[6]-a[0], e2y = a[7]-a[1], e2z = a[8]-a[2];
    float fnx = e1y*e2z - e1z*e2y;
    float fny = e1z*e2x - e1x*e2z;
    float fnz = e1x*e2y - e1y*e2x;
    atomicAdd(&vnAcc[f0*3+0], fnx); atomicAdd(&vnAcc[f0*3+1], fny); atomicAdd(&vnAcc[f0*3+2], fnz);
    atomicAdd(&vnAcc[f1*3+0], fnx); atomicAdd(&vnAcc[f1*3+1], fny); atomicAdd(&vnAcc[f1*3+2], fnz);
    atomicAdd(&vnAcc[f2*3+0], fnx); atomicAdd(&vnAcc[f2*3+1], fny); atomicAdd(&vnAcc[f2*3+2], fnz);
    a[9]  = vcol[f0*3+0]; a[10] = vcol[f0*3+1]; a[11] = vcol[f0*3+2];
    a[12] = vcol[f1*3+0]; a[13] = vcol[f1*3+1]; a[14] = vcol[f1*3+2];
    a[15] = vcol[f2*3+0]; a[16] = vcol[f2*3+1]; a[17] = vcol[f2*3+2];
    __half2* o = fd + (size_t)i * 16;   // 16 half2 words per face
    #pragma unroll
    for (int t = 0; t < 9; ++t) o[t] = __floats2half2_rn(a[2*t], a[2*t+1]);
}

__global__ __launch_bounds__(256)
void face_pass2(const int* __restrict__ faces,
                const float* __restrict__ vn,
                __half2* __restrict__ fd) {
    int i = blockIdx.x * blockDim.x + threadIdx.x;
    if (i >= FC_) return;
    int fidx[3] = { faces[i*3+0], faces[i*3+1], faces[i*3+2] };
    float b[10];
    #pragma unroll
    for (int v = 0; v < 3; ++v) {
        float x = vn[fidx[v]*3+0], y = vn[fidx[v]*3+1], z = vn[fidx[v]*3+2];
        float inv = 1.0f / fmaxf(sqrtf(x*x + y*y + z*z), 1e-6f);
        b[v*3+0] = x*inv; b[v*3+1] = y*inv; b[v*3+2] = z*inv;
    }
    b[9] = 0.0f;
    __half2* o = fd + (size_t)i * 16 + 9;   // words 9..13 = halfs 18..27
    #pragma unroll
    for (int t = 0; t < 5; ++t) o[t] = __floats2half2_rn(b[2*t], b[2*t+1]);
}

__global__ __launch_bounds__(256)
void pixel_kernel(const int*   __restrict__ ptf,
                  const float* __restrict__ bary,
                  const float* __restrict__ dists,
                  const float* __restrict__ zbuf,
                  const ushort* __restrict__ fd16,
                  const float* __restrict__ light,
                  const float* __restrict__ amb,
                  const float* __restrict__ dif,
                  const float* __restrict__ spec,
                  const float* __restrict__ cam,
                  float* __restrict__ out) {
    int tid = blockIdx.x * blockDim.x + threadIdx.x;
    int pix = tid >> 5;        // 32 lanes per pixel
    int j   = tid & 31;        // lane-in-pixel; j<28 active
    if (pix >= NPIX) return;

    bool act = (j < K_);
    size_t sbase = (size_t)pix * K_ + j;

    int pf = -1;
    float d = 0.0f, z = 0.0f, w0 = 0.0f, w1 = 0.0f, w2 = 0.0f;
    if (act) {
        pf = ptf[sbase];
        d  = dists[sbase];
        z  = zbuf[sbase];
        w0 = bary[sbase*3+0];
        w1 = bary[sbase*3+1];
        w2 = bary[sbase*3+2];
        out[(size_t)NPIX*4 + sbase] = z;   // zbuf passthrough
    }

    float zi = 0.0f, prob = 0.0f, cr = 0.0f, cg = 0.0f, cb = 0.0f;
    if (pf >= 0) {
        prob = 1.0f / (1.0f + expf(d * SIGMA_INV));   // sigmoid(-d/sigma)
        zi   = (ZFAR_ - z) * ZSCALE;

        const uint4* fq = (const uint4*)(fd16 + (size_t)pf * 32);
        union { uint4 u[4]; __half h[32]; } F;
        F.u[0] = fq[0]; F.u[1] = fq[1]; F.u[2] = fq[2]; F.u[3] = fq[3];

        float p0x = __half2float(F.h[0]),  p0y = __half2float(F.h[1]),  p0z = __half2float(F.h[2]);
        float p1x = __half2float(F.h[3]),  p1y = __half2float(F.h[4]),  p1z = __half2float(F.h[5]);
        float p2x = __half2float(F.h[6]),  p2y = __half2float(F.h[7]),  p2z = __half2float(F.h[8]);
        float c0x = __half2float(F.h[9]),  c0y = __half2float(F.h[10]), c0z = __half2float(F.h[11]);
        float c1x = __half2float(F.h[12]), c1y = __half2float(F.h[13]), c1z = __half2float(F.h[14]);
        float c2x = __half2float(F.h[15]), c2y = __half2float(F.h[16]), c2z = __half2float(F.h[17]);
        float n0x = __half2float(F.h[18]), n0y = __half2float(F.h[19]), n0z = __half2float(F.h[20]);
        float n1x = __half2float(F.h[21]), n1y = __half2float(F.h[22]), n1z = __half2float(F.h[23]);
        float n2x = __half2float(F.h[24]), n2y = __half2float(F.h[25]), n2z = __half2float(F.h[26]);

        float px = w0*p0x + w1*p1x + w2*p2x;
        float py = w0*p0y + w1*p1y + w2*p2y;
        float pz = w0*p0z + w1*p1z + w2*p2z;
        float nux = w0*n0x + w1*n1x + w2*n2x;
        float nuy = w0*n0y + w1*n1y + w2*n2y;
        float nuz = w0*n0z + w1*n1z + w2*n2z;
        float ninv = 1.0f / fmaxf(sqrtf(nux*nux + nuy*nuy + nuz*nuz), 1e-6f);
        float nx = nux*ninv, ny = nuy*ninv, nz = nuz*ninv;
        float tr = w0*c0x + w1*c1x + w2*c2x;
        float tg = w0*c0y + w1*c1y + w2*c2y;
        float tb = w0*c0z + w1*c1z + w2*c2z;

        float lvx = light[0] - px, lvy = light[1] - py, lvz = light[2] - pz;
        float linv = 1.0f / fmaxf(sqrtf(lvx*lvx + lvy*lvy + lvz*lvz), 1e-6f);
        lvx *= linv; lvy *= linv; lvz *= linv;
        float ldn = lvx*nx + lvy*ny + lvz*nz;
        float ndotl = fmaxf(ldn, 0.0f);

        float vvx = cam[0] - px, vvy = cam[1] - py, vvz = cam[2] - pz;
        float vinv = 1.0f / fmaxf(sqrtf(vvx*vvx + vvy*vvy + vvz*vvz), 1e-6f);
        vvx *= vinv; vvy *= vinv; vvz *= vinv;

        float rx = 2.0f*ldn*nx - lvx;
        float ry = 2.0f*ldn*ny - lvy;
        float rz = 2.0f*ldn*nz - lvz;
        float ca = fmaxf(rx*vvx + ry*vvy + rz*vvz, 0.0f);
        float p64 = ca*ca; p64 *= p64; p64 *= p64; p64 *= p64; p64 *= p64; p64 *= p64;

        cr = (amb[0] + dif[0]*ndotl)*tr + spec[0]*p64;
        cg = (amb[1] + dif[1]*ndotl)*tg + spec[1]*p64;
        cb = (amb[2] + dif[2]*ndotl)*tb + spec[2]*p64;
    }

    // ---- subgroup (32-lane) reductions: exact two-pass softmax-style blend
    float m = fmaxf(zi, EPS_);
    #pragma unroll
    for (int o = 16; o; o >>= 1) m = fmaxf(m, __shfl_xor(m, o, 32));

    float w = prob * expf((zi - m) * GAMMA_INV);   // underflows to 0 safely
    float swr = w * cr, swg = w * cg, swb = w * cb;
    float om  = 1.0f - prob;
    #pragma unroll
    for (int o = 16; o; o >>= 1) {
        w   += __shfl_xor(w,   o, 32);
        swr += __shfl_xor(swr, o, 32);
        swg += __shfl_xor(swg, o, 32);
        swb += __shfl_xor(swb, o, 32);
        om  *= __shfl_xor(om,  o, 32);
    }

    if (j == 0) {
        float deltaw = expf((EPS_ - m) * GAMMA_INV);
        float inv = 1.0f / (w + deltaw);
        float4 img;
        img.x = (swr + deltaw) * inv;   // BG = 1
        img.y = (swg + deltaw) * inv;
        img.z = (swb + deltaw) * inv;
        img.w = 1.0f - om;
        ((float4*)out)[pix] = img;
    }
}

extern "C" void kernel_launch(void* const* d_in, const int* in_sizes, int n_in,
                              void* d_out, int out_size, void* d_ws, size_t ws_size,
                              hipStream_t stream) {
    const float* verts = (const float*)d_in[0];
    const float* vcol  = (const float*)d_in[1];
    const int*   faces = (const int*)d_in[2];
    const int*   ptf   = (const int*)d_in[3];
    const float* bary  = (const float*)d_in[4];
    const float* dists = (const float*)d_in[5];
    const float* zbuf  = (const float*)d_in[6];
    const float* light = (const float*)d_in[7];
    const float* amb   = (const float*)d_in[8];
    const float* dif   = (const float*)d_in[9];
    const float* spec  = (const float*)d_in[10];
    const float* cam   = (const float*)d_in[11];
    float* out = (float*)d_out;

    float*   vnAcc = (float*)d_ws;
    __half2* fdat  = (__half2*)((char*)d_ws + FD_OFFSET);

    hipMemsetAsync(vnAcc, 0, (size_t)V_ * 3 * sizeof(float), stream);
    face_pass1<<<(FC_ + 255)/256, 256, 0, stream>>>(verts, vcol, faces, vnAcc, fdat);
    face_pass2<<<(FC_ + 255)/256, 256, 0, stream>>>(faces, vnAcc, fdat);

    int blocks = (NPIX * 32 + 255) / 256;
    pixel_kernel<<<blocks, 256, 0, stream>>>(
        ptf, bary, dists, zbuf, (const ushort*)fdat,
        light, amb, dif, spec, cam, out);
}